// Round 3
// baseline (84.387 us; speedup 1.0000x reference)
//
#include <hip/hip_runtime.h>

typedef float v2f __attribute__((ext_vector_type(2)));

#define NPTS     8192
#define GSIZE    16384               // 128*128 grid
#define NSEG     64                  // point segments (across blocks)
#define SEGPTS   (NPTS / NSEG)       // 128 points per segment
#define SEGPAIRS (SEGPTS / 2)        // 64 point-pairs per segment
#define NPAIRS   (NPTS / 2)          // 4096
#define GPB      1024                // grid points per block
#define GPT      4                   // grid points per thread
#define NGB      (GSIZE / GPB)       // 16 grid-blocks
#define L2E      1.4426950408889634f

// ws layout (floats): partials, then 5 pair-interleaved SoA arrays
#define PART_F   (NSEG * 3 * GSIZE)  // 3,145,728 floats (12.6 MB)
#define ARR_F    (NPAIRS * 2)        // 8192 floats per array
#define OFF_X0   (PART_F)
#define OFF_X1   (OFF_X0 + ARR_F)
#define OFF_BX   (OFF_X1 + ARR_F)
#define OFF_Y0   (OFF_BX + ARR_F)
#define OFF_Y1   (OFF_Y0 + ARR_F)
#define WS_FLOATS (OFF_Y1 + ARR_F)
#define WS_NEEDED ((size_t)WS_FLOATS * sizeof(float))

// -------- K0: transform points into pair-interleaved SoA (scalar-load food) --
__global__ __launch_bounds__(256) void convcnp_k0(
    const float* __restrict__ X, const float* __restrict__ Y, float* __restrict__ ws)
{
    int jp = blockIdx.x * 256 + threadIdx.x;      // 16 blocks, 4096 pairs
    float4 x = ((const float4*)X)[jp];            // {x0a, x1a, x0b, x1b}
    float4 y = ((const float4*)Y)[jp];            // {y0a, y1a, y0b, y1b}
    float bxa = -0.5f * (x.x * x.x + x.y * x.y);
    float bxb = -0.5f * (x.z * x.z + x.w * x.w);
    ((v2f*)(ws + OFF_X0))[jp] = (v2f){x.x * L2E, x.z * L2E};
    ((v2f*)(ws + OFF_X1))[jp] = (v2f){x.y * L2E, x.w * L2E};
    ((v2f*)(ws + OFF_BX))[jp] = (v2f){bxa * L2E, bxb * L2E};
    ((v2f*)(ws + OFF_Y0))[jp] = (v2f){y.x, y.z};
    ((v2f*)(ws + OFF_Y1))[jp] = (v2f){y.y, y.w};
}

// -------- K1: packed-fp32 partial sums; point data via scalar (SMEM) loads --
__global__ __launch_bounds__(256, 4) void convcnp_k1(
    const v2f* __restrict__ X0, const v2f* __restrict__ X1,
    const v2f* __restrict__ BX, const v2f* __restrict__ Y0,
    const v2f* __restrict__ Y1, float* __restrict__ part)
{
    const int tid = threadIdx.x;
    const int gb  = blockIdx.x & (NGB - 1);
    const int seg = blockIdx.x >> 4;

    v2f gx2[GPT], gy2[GPT], s0[GPT], s1[GPT], s2[GPT];
    #pragma unroll
    for (int k = 0; k < GPT; ++k) {
        int gi = gb * GPB + k * 256 + tid;        // flat grid index = ix*128+iy
        int ix = gi >> 7, iy = gi & 127;
        float gx = -2.0f + (float)ix * (4.0f / 127.0f);
        float gy = -2.0f + (float)iy * (4.0f / 127.0f);
        gx2[k] = (v2f){gx, gx};
        gy2[k] = (v2f){gy, gy};
        s0[k] = (v2f){0.f, 0.f}; s1[k] = (v2f){0.f, 0.f}; s2[k] = (v2f){0.f, 0.f};
    }

    const int base = seg * SEGPAIRS;
    #pragma unroll 4
    for (int jp = 0; jp < SEGPAIRS; ++jp) {
        v2f x0 = X0[base + jp];   // uniform address -> s_load, SGPR operands
        v2f x1 = X1[base + jp];
        v2f bx = BX[base + jp];
        v2f y0 = Y0[base + jp];
        v2f y1 = Y1[base + jp];
        #pragma unroll
        for (int k = 0; k < GPT; ++k) {
            v2f t = __builtin_elementwise_fma(gy2[k], x1, bx);   // v_pk_fma_f32
            t     = __builtin_elementwise_fma(gx2[k], x0, t);
            v2f E;
            E.x = __builtin_amdgcn_exp2f(t.x);
            E.y = __builtin_amdgcn_exp2f(t.y);
            s0[k] += E;                                          // v_pk_add_f32
            s1[k] = __builtin_elementwise_fma(E, y0, s1[k]);
            s2[k] = __builtin_elementwise_fma(E, y1, s2[k]);
        }
    }

    #pragma unroll
    for (int k = 0; k < GPT; ++k) {
        int gi = gb * GPB + k * 256 + tid;        // coalesced stores
        part[(seg * 3 + 0) * GSIZE + gi] = s0[k].x + s0[k].y;
        part[(seg * 3 + 1) * GSIZE + gi] = s1[k].x + s1[k].y;
        part[(seg * 3 + 2) * GSIZE + gi] = s2[k].x + s2[k].y;
    }
}

// -------- K2: reduce segments, scale, divide, transpose-store ---------------
__global__ __launch_bounds__(64) void convcnp_k2(
    const float* __restrict__ part, float* __restrict__ out)
{
    int g = blockIdx.x * 64 + threadIdx.x;        // 256 blocks x 1 wave
    float s0 = 0.0f, s1 = 0.0f, s2 = 0.0f;
    #pragma unroll 16
    for (int s = 0; s < NSEG; ++s) {              // coalesced dword loads
        s0 += part[(s * 3 + 0) * GSIZE + g];
        s1 += part[(s * 3 + 1) * GSIZE + g];
        s2 += part[(s * 3 + 2) * GSIZE + g];
    }
    int ix = g >> 7, iy = g & 127;
    float gx = -2.0f + (float)ix * (4.0f / 127.0f);
    float gy = -2.0f + (float)iy * (4.0f / 127.0f);
    float eg = __builtin_amdgcn_exp2f(-0.5f * L2E * (gx * gx + gy * gy));
    float inv = 1.0f / s0;
    int o = iy * 128 + ix;                        // (3, n_y, n_x)
    out[o]             = eg * s0;                 // denom channel: not divided
    out[GSIZE + o]     = s1 * inv;                // eg cancels in the ratio
    out[2 * GSIZE + o] = s2 * inv;
}

// -------- Fallback: proven R1 single-kernel (if ws too small) ---------------
#define TS 1024
#define NTILES (NPTS / TS)
__global__ __launch_bounds__(256, 4) void convcnp_fallback(
    const float* __restrict__ X, const float* __restrict__ Y, float* __restrict__ out)
{
    __shared__ float4 tile[TS];
    const int tid = threadIdx.x;
    const int g   = tid >> 4;
    const int sg  = tid & 15;
    const int gi = blockIdx.x * 16 + g;
    const int ix = gi >> 7, iy = gi & 127;
    const float gx = -2.0f + (float)ix * (4.0f / 127.0f);
    const float gy = -2.0f + (float)iy * (4.0f / 127.0f);
    float s0 = 0.0f, s1 = 0.0f, s2 = 0.0f;
    const float4* X4 = (const float4*)X;
    const float4* Y4 = (const float4*)Y;
    for (int t = 0; t < NTILES; ++t) {
        #pragma unroll
        for (int i = 0; i < TS / 2; i += 256) {
            float4 xa = X4[t * (TS / 2) + i + tid];
            float4 ya = Y4[t * (TS / 2) + i + tid];
            int p = 2 * (i + tid);
            tile[p]     = make_float4(xa.x, xa.y, ya.x, ya.y);
            tile[p + 1] = make_float4(xa.z, xa.w, ya.z, ya.w);
        }
        __syncthreads();
        #pragma unroll 8
        for (int j = 0; j < TS / 16; ++j) {
            float4 p = tile[j * 16 + sg];
            float dx = gx - p.x, dy = gy - p.y;
            float k = __expf(-0.5f * (dx * dx + dy * dy));
            s0 += k; s1 += k * p.z; s2 += k * p.w;
        }
        __syncthreads();
    }
    #pragma unroll
    for (int off = 8; off >= 1; off >>= 1) {
        s0 += __shfl_down(s0, off, 16);
        s1 += __shfl_down(s1, off, 16);
        s2 += __shfl_down(s2, off, 16);
    }
    if (sg == 0) {
        const int o = iy * 128 + ix;
        float inv = 1.0f / s0;
        out[o] = s0; out[GSIZE + o] = s1 * inv; out[2 * GSIZE + o] = s2 * inv;
    }
}

extern "C" void kernel_launch(void* const* d_in, const int* in_sizes, int n_in,
                              void* d_out, int out_size, void* d_ws, size_t ws_size,
                              hipStream_t stream) {
    const float* X = (const float*)d_in[0];
    const float* Y = (const float*)d_in[1];
    float* out = (float*)d_out;
    if (ws_size >= WS_NEEDED) {
        float* ws = (float*)d_ws;
        convcnp_k0<<<NPAIRS / 256, 256, 0, stream>>>(X, Y, ws);
        convcnp_k1<<<NGB * NSEG, 256, 0, stream>>>(
            (const v2f*)(ws + OFF_X0), (const v2f*)(ws + OFF_X1),
            (const v2f*)(ws + OFF_BX), (const v2f*)(ws + OFF_Y0),
            (const v2f*)(ws + OFF_Y1), ws);
        convcnp_k2<<<GSIZE / 64, 64, 0, stream>>>(ws, out);
    } else {
        convcnp_fallback<<<GSIZE / 16, 256, 0, stream>>>(X, Y, out);
    }
}

// Round 4
// 76.486 us; speedup vs baseline: 1.1033x; 1.1033x over previous
//
#include <hip/hip_runtime.h>

typedef __attribute__((ext_vector_type(8))) short s16x8;   // 8 bf16 (4 VGPRs)
typedef __attribute__((ext_vector_type(4))) float f32x4;

#define NPTS   8192
#define GSIZE  16384
#define L2E    1.4426950408889634f
#define NHL2E  (-0.7213475204444817f)   // -0.5 * log2(e)
#define NSPLIT 16
#define KCH    (NPTS / NSPLIT)          // 512

// ws layout (bytes)
#define A_OFF  0                        // A: 128 x 8192 bf16 = 2 MB
#define B_OFF  (128 * 8192 * 2)         // B: 384 x 8192 bf16 = 6 MB (B0, B0*y0, B0*y1)
#define P_OFF  (B_OFF + 384 * 8192 * 2) // partials: 16 x 384 x 128 f32 = 3 MB
#define WS_NEEDED ((size_t)P_OFF + (size_t)NSPLIT * 384 * 128 * 4)

__device__ __forceinline__ short f2bf(float f) {   // RNE float->bf16 bits
    unsigned int u = __builtin_bit_cast(unsigned int, f);
    u += 0x7FFF + ((u >> 16) & 1);
    return (short)(u >> 16);
}

// ---- K1: generate A[ix][j] and B-stack rows (exp count: 2.1M, was 134M) ----
__global__ __launch_bounds__(256) void gen_kernel(
    const float* __restrict__ X, const float* __restrict__ Y,
    unsigned short* __restrict__ Amat, unsigned short* __restrict__ Bmat)
{
    const int b = blockIdx.x, tid = threadIdx.x;
    const float4* X4 = (const float4*)X;   // {xj0, xj1, x(j+1)0, x(j+1)1}
    const float4* Y4 = (const float4*)Y;
    if (b < 512) {                          // A-part: 128 rows x 4 blocks/row
        int ix = b >> 2;
        int j0 = (b & 3) * 2048 + tid * 8;
        float gx = -2.0f + (float)ix * (4.0f / 127.0f);
        s16x8 v;
        #pragma unroll
        for (int i = 0; i < 4; ++i) {
            float4 p = X4[(j0 >> 1) + i];
            float d0 = gx - p.x, d1 = gx - p.z;
            v[2*i]   = f2bf(__builtin_amdgcn_exp2f(d0 * d0 * NHL2E));
            v[2*i+1] = f2bf(__builtin_amdgcn_exp2f(d1 * d1 * NHL2E));
        }
        *(s16x8*)(Amat + ix * NPTS + j0) = v;
    } else {                                // B-part: writes B0, B0*y0, B0*y1
        int bb = b - 512;
        int iy = bb >> 2;
        int j0 = (bb & 3) * 2048 + tid * 8;
        float gy = -2.0f + (float)iy * (4.0f / 127.0f);
        s16x8 v0, v1, v2;
        #pragma unroll
        for (int i = 0; i < 4; ++i) {
            float4 p = X4[(j0 >> 1) + i];
            float4 q = Y4[(j0 >> 1) + i];
            float d0 = gy - p.y, d1 = gy - p.w;
            float e0 = __builtin_amdgcn_exp2f(d0 * d0 * NHL2E);
            float e1 = __builtin_amdgcn_exp2f(d1 * d1 * NHL2E);
            v0[2*i] = f2bf(e0);        v0[2*i+1] = f2bf(e1);
            v1[2*i] = f2bf(e0 * q.x);  v1[2*i+1] = f2bf(e1 * q.z);
            v2[2*i] = f2bf(e0 * q.y);  v2[2*i+1] = f2bf(e1 * q.w);
        }
        *(s16x8*)(Bmat + iy * NPTS + j0)          = v0;
        *(s16x8*)(Bmat + (128 + iy) * NPTS + j0)  = v1;
        *(s16x8*)(Bmat + (256 + iy) * NPTS + j0)  = v2;
    }
}

// ---- K2: C[m=ix][n=c*128+iy] = A @ B^T via MFMA, split-K=16 ----------------
// A-frag: m=lane&15, k=quad*8+j ; B-frag: n=lane&15, same k (both K-major).
// C/D: col(n)=lane&15, row(m)=quad*4+reg  [verified m89/m91].
__global__ __launch_bounds__(256) void gemm_kernel(
    const unsigned short* __restrict__ Amat,
    const unsigned short* __restrict__ Bmat,
    float* __restrict__ part)
{
    const int tid = threadIdx.x;
    const int lane = tid & 63, wv = tid >> 6;
    const int g = blockIdx.x;
    const int s  = g & (NSPLIT - 1);
    const int tg = g >> 4;                  // 0..47
    const int tile = tg * 4 + wv;           // 0..191 (8 mtiles x 24 ntiles)
    const int mt = tile & 7, nt = tile >> 3;
    const int r = lane & 15, quad = lane >> 4;

    const unsigned short* ap = Amat + (mt * 16 + r) * NPTS + s * KCH + quad * 8;
    const unsigned short* bp = Bmat + (nt * 16 + r) * NPTS + s * KCH + quad * 8;

    f32x4 acc = {0.f, 0.f, 0.f, 0.f};
    #pragma unroll 8
    for (int kk = 0; kk < KCH; kk += 32) {
        s16x8 a = *(const s16x8*)(ap + kk);
        s16x8 b = *(const s16x8*)(bp + kk);
        acc = __builtin_amdgcn_mfma_f32_16x16x32_bf16(a, b, acc, 0, 0, 0);
    }
    // partials layout [s][n(384)][m(128)]; acc regs are m-consecutive -> float4
    f32x4* dst = (f32x4*)(part + s * (384 * 128) + (nt * 16 + r) * 128
                          + mt * 16 + quad * 4);
    *dst = acc;
}

// ---- K3: sum splits, divide, store; reads AND writes unit-stride -----------
__global__ __launch_bounds__(256) void reduce_kernel(
    const float* __restrict__ part, float* __restrict__ out)
{
    int t = blockIdx.x * 256 + threadIdx.x;   // t = iy*128+ix, 64 blocks
    float f0 = 0.f, f1 = 0.f, f2 = 0.f;
    #pragma unroll
    for (int s = 0; s < NSPLIT; ++s) {
        const float* p = part + s * (384 * 128);
        f0 += p[t];                 // n = iy        (c=0)
        f1 += p[16384 + t];         // n = 128+iy    (c=1)
        f2 += p[32768 + t];         // n = 256+iy    (c=2)
    }
    float inv = 1.0f / f0;
    out[t]          = f0;           // denom channel: NOT divided
    out[16384 + t]  = f1 * inv;
    out[32768 + t]  = f2 * inv;
}

// ---- Fallback: proven R1 single-kernel (if ws too small) -------------------
#define TS 1024
__global__ __launch_bounds__(256, 4) void convcnp_fallback(
    const float* __restrict__ X, const float* __restrict__ Y, float* __restrict__ out)
{
    __shared__ float4 tile[TS];
    const int tid = threadIdx.x;
    const int gq  = tid >> 4;
    const int sg  = tid & 15;
    const int gi = blockIdx.x * 16 + gq;
    const int ix = gi >> 7, iy = gi & 127;
    const float gx = -2.0f + (float)ix * (4.0f / 127.0f);
    const float gy = -2.0f + (float)iy * (4.0f / 127.0f);
    float s0 = 0.f, s1 = 0.f, s2 = 0.f;
    const float4* X4 = (const float4*)X;
    const float4* Y4 = (const float4*)Y;
    for (int t = 0; t < NPTS / TS; ++t) {
        #pragma unroll
        for (int i = 0; i < TS / 2; i += 256) {
            float4 xa = X4[t * (TS / 2) + i + tid];
            float4 ya = Y4[t * (TS / 2) + i + tid];
            int p = 2 * (i + tid);
            tile[p]     = make_float4(xa.x, xa.y, ya.x, ya.y);
            tile[p + 1] = make_float4(xa.z, xa.w, ya.z, ya.w);
        }
        __syncthreads();
        #pragma unroll 8
        for (int j = 0; j < TS / 16; ++j) {
            float4 p = tile[j * 16 + sg];
            float dx = gx - p.x, dy = gy - p.y;
            float k = __expf(-0.5f * (dx * dx + dy * dy));
            s0 += k; s1 += k * p.z; s2 += k * p.w;
        }
        __syncthreads();
    }
    #pragma unroll
    for (int off = 8; off >= 1; off >>= 1) {
        s0 += __shfl_down(s0, off, 16);
        s1 += __shfl_down(s1, off, 16);
        s2 += __shfl_down(s2, off, 16);
    }
    if (sg == 0) {
        const int o = iy * 128 + ix;
        float inv = 1.0f / s0;
        out[o] = s0; out[GSIZE + o] = s1 * inv; out[2 * GSIZE + o] = s2 * inv;
    }
}

extern "C" void kernel_launch(void* const* d_in, const int* in_sizes, int n_in,
                              void* d_out, int out_size, void* d_ws, size_t ws_size,
                              hipStream_t stream) {
    const float* X = (const float*)d_in[0];
    const float* Y = (const float*)d_in[1];
    float* out = (float*)d_out;
    if (ws_size >= WS_NEEDED) {
        unsigned short* Amat = (unsigned short*)((char*)d_ws + A_OFF);
        unsigned short* Bmat = (unsigned short*)((char*)d_ws + B_OFF);
        float* part = (float*)((char*)d_ws + P_OFF);
        gen_kernel<<<1024, 256, 0, stream>>>(X, Y, Amat, Bmat);
        gemm_kernel<<<48 * NSPLIT, 256, 0, stream>>>(Amat, Bmat, part);
        reduce_kernel<<<GSIZE / 256, 256, 0, stream>>>(part, out);
    } else {
        convcnp_fallback<<<GSIZE / 16, 256, 0, stream>>>(X, Y, out);
    }
}

// Round 5
// 73.738 us; speedup vs baseline: 1.1444x; 1.0373x over previous
//
#include <hip/hip_runtime.h>

typedef __attribute__((ext_vector_type(8))) short s16x8;   // 8 bf16 (4 VGPRs)
typedef __attribute__((ext_vector_type(4))) float f32x4;

#define NPTS   8192
#define GSIZE  16384
#define NHL2E  (-0.7213475204444817f)   // -0.5 * log2(e)
#define NSPLIT 16
#define KCH    (NPTS / NSPLIT)          // 512

// ws layout (bytes)
#define A_OFF  0                        // A: 128 x 8192 bf16 = 2 MB
#define B_OFF  (128 * 8192 * 2)         // B: 384 x 8192 bf16 = 6 MB (B0, B0*y0, B0*y1)
#define P_OFF  (B_OFF + 384 * 8192 * 2) // partials: 16 x 384 x 128 f32 = 3 MB
#define WS_NEEDED ((size_t)P_OFF + (size_t)NSPLIT * 384 * 128 * 4)

__device__ __forceinline__ short f2bf(float f) {   // RNE float->bf16 bits
    unsigned int u = __builtin_bit_cast(unsigned int, f);
    u += 0x7FFF + ((u >> 16) & 1);
    return (short)(u >> 16);
}

// ---- K1: generate A[ix][j] and B-stack rows (2.1M exps, was 134M) ----------
__global__ __launch_bounds__(256) void gen_kernel(
    const float* __restrict__ X, const float* __restrict__ Y,
    unsigned short* __restrict__ Amat, unsigned short* __restrict__ Bmat)
{
    const int b = blockIdx.x, tid = threadIdx.x;
    const float4* X4 = (const float4*)X;   // {xj0, xj1, x(j+1)0, x(j+1)1}
    const float4* Y4 = (const float4*)Y;
    if (b < 512) {                          // A-part: 128 rows x 4 blocks/row
        int ix = b >> 2;
        int j0 = (b & 3) * 2048 + tid * 8;
        float gx = -2.0f + (float)ix * (4.0f / 127.0f);
        s16x8 v;
        #pragma unroll
        for (int i = 0; i < 4; ++i) {
            float4 p = X4[(j0 >> 1) + i];
            float d0 = gx - p.x, d1 = gx - p.z;
            v[2*i]   = f2bf(__builtin_amdgcn_exp2f(d0 * d0 * NHL2E));
            v[2*i+1] = f2bf(__builtin_amdgcn_exp2f(d1 * d1 * NHL2E));
        }
        *(s16x8*)(Amat + ix * NPTS + j0) = v;
    } else {                                // B-part: writes B0, B0*y0, B0*y1
        int bb = b - 512;
        int iy = bb >> 2;
        int j0 = (bb & 3) * 2048 + tid * 8;
        float gy = -2.0f + (float)iy * (4.0f / 127.0f);
        s16x8 v0, v1, v2;
        #pragma unroll
        for (int i = 0; i < 4; ++i) {
            float4 p = X4[(j0 >> 1) + i];
            float4 q = Y4[(j0 >> 1) + i];
            float d0 = gy - p.y, d1 = gy - p.w;
            float e0 = __builtin_amdgcn_exp2f(d0 * d0 * NHL2E);
            float e1 = __builtin_amdgcn_exp2f(d1 * d1 * NHL2E);
            v0[2*i] = f2bf(e0);        v0[2*i+1] = f2bf(e1);
            v1[2*i] = f2bf(e0 * q.x);  v1[2*i+1] = f2bf(e1 * q.z);
            v2[2*i] = f2bf(e0 * q.y);  v2[2*i+1] = f2bf(e1 * q.w);
        }
        *(s16x8*)(Bmat + iy * NPTS + j0)          = v0;
        *(s16x8*)(Bmat + (128 + iy) * NPTS + j0)  = v1;
        *(s16x8*)(Bmat + (256 + iy) * NPTS + j0)  = v2;
    }
}

// ---- K2: wave tile = 16m x 48n (3 channels of one iy-tile), split-K=16 -----
// Per kk-step: 1 A-load + 3 B-loads + 3 MFMAs. Traffic 64 MB (was 96).
// 1024 wave-jobs = 256 blocks x 4 waves; waves of a block share (mt,iyt).
// C/D: col(n)=lane&15, row(m)=quad*4+reg  [verified m89/m91].
__global__ __launch_bounds__(256) void gemm_kernel(
    const unsigned short* __restrict__ Amat,
    const unsigned short* __restrict__ Bmat,
    float* __restrict__ part)
{
    const int tid = threadIdx.x;
    const int lane = tid & 63, wv = tid >> 6;
    const int job  = blockIdx.x * 4 + wv;     // 0..1023
    const int s    = job & (NSPLIT - 1);
    const int rest = job >> 4;                // 0..63
    const int mt = rest & 7, iyt = rest >> 3;
    const int r = lane & 15, quad = lane >> 4;

    const unsigned short* ap = Amat + (mt * 16 + r) * NPTS + s * KCH + quad * 8;
    const unsigned short* bp = Bmat + (iyt * 16 + r) * NPTS + s * KCH + quad * 8;

    f32x4 a0 = {0.f,0.f,0.f,0.f}, a1 = a0, a2 = a0;
    #pragma unroll 4
    for (int kk = 0; kk < KCH; kk += 32) {
        s16x8 a  = *(const s16x8*)(ap + kk);
        s16x8 b0 = *(const s16x8*)(bp + kk);
        s16x8 b1 = *(const s16x8*)(bp + 128 * NPTS + kk);
        s16x8 b2 = *(const s16x8*)(bp + 256 * NPTS + kk);
        a0 = __builtin_amdgcn_mfma_f32_16x16x32_bf16(a, b0, a0, 0, 0, 0);
        a1 = __builtin_amdgcn_mfma_f32_16x16x32_bf16(a, b1, a1, 0, 0, 0);
        a2 = __builtin_amdgcn_mfma_f32_16x16x32_bf16(a, b2, a2, 0, 0, 0);
    }
    // partials [s][n(384)][m(128)]; acc regs m-consecutive -> float4 stores
    float* base = part + s * (384 * 128);
    int row = iyt * 16 + r, col = mt * 16 + quad * 4;
    *(f32x4*)(base + (row)       * 128 + col) = a0;
    *(f32x4*)(base + (128 + row) * 128 + col) = a1;
    *(f32x4*)(base + (256 + row) * 128 + col) = a2;
}

// ---- K3: sum splits, divide, store; 256 blocks (all CUs) -------------------
__global__ __launch_bounds__(64) void reduce_kernel(
    const float* __restrict__ part, float* __restrict__ out)
{
    int t = blockIdx.x * 64 + threadIdx.x;    // t = iy*128+ix, 256 blocks
    float f0 = 0.f, f1 = 0.f, f2 = 0.f;
    #pragma unroll
    for (int s = 0; s < NSPLIT; ++s) {
        const float* p = part + s * (384 * 128);
        f0 += p[t];                 // n = iy        (c=0)
        f1 += p[16384 + t];         // n = 128+iy    (c=1)
        f2 += p[32768 + t];         // n = 256+iy    (c=2)
    }
    float inv = 1.0f / f0;
    out[t]          = f0;           // denom channel: NOT divided
    out[16384 + t]  = f1 * inv;
    out[32768 + t]  = f2 * inv;
}

// ---- Fallback: proven R1 single-kernel (if ws too small) -------------------
#define TS 1024
__global__ __launch_bounds__(256, 4) void convcnp_fallback(
    const float* __restrict__ X, const float* __restrict__ Y, float* __restrict__ out)
{
    __shared__ float4 tile[TS];
    const int tid = threadIdx.x;
    const int gq  = tid >> 4;
    const int sg  = tid & 15;
    const int gi = blockIdx.x * 16 + gq;
    const int ix = gi >> 7, iy = gi & 127;
    const float gx = -2.0f + (float)ix * (4.0f / 127.0f);
    const float gy = -2.0f + (float)iy * (4.0f / 127.0f);
    float s0 = 0.f, s1 = 0.f, s2 = 0.f;
    const float4* X4 = (const float4*)X;
    const float4* Y4 = (const float4*)Y;
    for (int t = 0; t < NPTS / TS; ++t) {
        #pragma unroll
        for (int i = 0; i < TS / 2; i += 256) {
            float4 xa = X4[t * (TS / 2) + i + tid];
            float4 ya = Y4[t * (TS / 2) + i + tid];
            int p = 2 * (i + tid);
            tile[p]     = make_float4(xa.x, xa.y, ya.x, ya.y);
            tile[p + 1] = make_float4(xa.z, xa.w, ya.z, ya.w);
        }
        __syncthreads();
        #pragma unroll 8
        for (int j = 0; j < TS / 16; ++j) {
            float4 p = tile[j * 16 + sg];
            float dx = gx - p.x, dy = gy - p.y;
            float k = __expf(-0.5f * (dx * dx + dy * dy));
            s0 += k; s1 += k * p.z; s2 += k * p.w;
        }
        __syncthreads();
    }
    #pragma unroll
    for (int off = 8; off >= 1; off >>= 1) {
        s0 += __shfl_down(s0, off, 16);
        s1 += __shfl_down(s1, off, 16);
        s2 += __shfl_down(s2, off, 16);
    }
    if (sg == 0) {
        const int o = iy * 128 + ix;
        float inv = 1.0f / s0;
        out[o] = s0; out[GSIZE + o] = s1 * inv; out[2 * GSIZE + o] = s2 * inv;
    }
}

extern "C" void kernel_launch(void* const* d_in, const int* in_sizes, int n_in,
                              void* d_out, int out_size, void* d_ws, size_t ws_size,
                              hipStream_t stream) {
    const float* X = (const float*)d_in[0];
    const float* Y = (const float*)d_in[1];
    float* out = (float*)d_out;
    if (ws_size >= WS_NEEDED) {
        unsigned short* Amat = (unsigned short*)((char*)d_ws + A_OFF);
        unsigned short* Bmat = (unsigned short*)((char*)d_ws + B_OFF);
        float* part = (float*)((char*)d_ws + P_OFF);
        gen_kernel<<<1024, 256, 0, stream>>>(X, Y, Amat, Bmat);
        gemm_kernel<<<256, 256, 0, stream>>>(Amat, Bmat, part);
        reduce_kernel<<<GSIZE / 64, 64, 0, stream>>>(part, out);
    } else {
        convcnp_fallback<<<GSIZE / 16, 256, 0, stream>>>(X, Y, out);
    }
}

// Round 6
// 72.748 us; speedup vs baseline: 1.1600x; 1.0136x over previous
//
#include <hip/hip_runtime.h>

typedef __attribute__((ext_vector_type(8))) short s16x8;   // 8 bf16 (4 VGPRs)
typedef __attribute__((ext_vector_type(4))) float f32x4;

#define NPTS    8192
#define GSIZE   16384
#define NHL2E   (-0.7213475204444817f)   // -0.5 * log2(e)
#define KCH     512                      // K-chunk per block
#define NSPLITB 16                       // block-level splits (KCH each)
#define NSPLIT  64                       // wave-level splits (KCH/4 = 128 each)
#define LDB     520                      // LDS row pitch in shorts (512 + 8 pad)

#define WS_NEEDED ((size_t)NSPLIT * 384 * 128 * 4)   // 12.6 MB partials

__device__ __forceinline__ short f2bf(float f) {   // RNE float->bf16 bits
    unsigned int u = __builtin_bit_cast(unsigned int, f);
    u += 0x7FFF + ((u >> 16) & 1);
    return (short)(u >> 16);
}

// ---- K_A: fused generate(A,B in LDS) + MFMA, one (mt,iyt,s) tile per block -
// A[m][k] = exp(-.5(xs[mt*16+m]-X[k,0])^2), B_c[n][k] = exp(-.5(ys[iyt*16+n]
// -X[k,1])^2) * {1, Y[k,0], Y[k,1]}.  C[m][n,c] accumulated over k via MFMA.
__global__ __launch_bounds__(256) void fused_kernel(
    const float* __restrict__ X, const float* __restrict__ Y,
    float* __restrict__ part)
{
    __shared__ __align__(16) short As[16 * LDB];        // 16.6 KB
    __shared__ __align__(16) short Bs[3 * 16 * LDB];    // 49.9 KB

    const int tid = threadIdx.x;
    const int b   = blockIdx.x;           // 1024 blocks
    const int s   = b & (NSPLITB - 1);
    const int rest = b >> 4;
    const int mt = rest & 7, iyt = rest >> 3;

    const float4* X4 = (const float4*)X;  // {xj0, xj1, x(j+1)0, x(j+1)1}
    const float4* Y4 = (const float4*)Y;

    // --- gen phase: thread = 4 rows x 8 cols; rg=tid>>6, cb=tid&63 ----------
    const int rg = tid >> 6, cb = tid & 63;
    const int jj = cb * 8;                // col within 512-chunk
    const int jb = (s * KCH + jj) >> 1;   // float4 index into X/Y

    float4 px0 = X4[jb], px1 = X4[jb + 1], px2 = X4[jb + 2], px3 = X4[jb + 3];
    float4 py0 = Y4[jb], py1 = Y4[jb + 1], py2 = Y4[jb + 2], py3 = Y4[jb + 3];

    #pragma unroll
    for (int ri = 0; ri < 4; ++ri) {      // A rows rg*4+ri
        int rm = rg * 4 + ri;
        float gx = -2.0f + (float)(mt * 16 + rm) * (4.0f / 127.0f);
        s16x8 v;
        float d;
        d = gx - px0.x; v[0] = f2bf(__builtin_amdgcn_exp2f(d * d * NHL2E));
        d = gx - px0.z; v[1] = f2bf(__builtin_amdgcn_exp2f(d * d * NHL2E));
        d = gx - px1.x; v[2] = f2bf(__builtin_amdgcn_exp2f(d * d * NHL2E));
        d = gx - px1.z; v[3] = f2bf(__builtin_amdgcn_exp2f(d * d * NHL2E));
        d = gx - px2.x; v[4] = f2bf(__builtin_amdgcn_exp2f(d * d * NHL2E));
        d = gx - px2.z; v[5] = f2bf(__builtin_amdgcn_exp2f(d * d * NHL2E));
        d = gx - px3.x; v[6] = f2bf(__builtin_amdgcn_exp2f(d * d * NHL2E));
        d = gx - px3.z; v[7] = f2bf(__builtin_amdgcn_exp2f(d * d * NHL2E));
        *(s16x8*)(As + rm * LDB + jj) = v;
    }

    #pragma unroll
    for (int ri = 0; ri < 4; ++ri) {      // B rows rg*4+ri, 3 channels
        int rn = rg * 4 + ri;
        float gy = -2.0f + (float)(iyt * 16 + rn) * (4.0f / 127.0f);
        float e[8], d;
        d = gy - px0.y; e[0] = __builtin_amdgcn_exp2f(d * d * NHL2E);
        d = gy - px0.w; e[1] = __builtin_amdgcn_exp2f(d * d * NHL2E);
        d = gy - px1.y; e[2] = __builtin_amdgcn_exp2f(d * d * NHL2E);
        d = gy - px1.w; e[3] = __builtin_amdgcn_exp2f(d * d * NHL2E);
        d = gy - px2.y; e[4] = __builtin_amdgcn_exp2f(d * d * NHL2E);
        d = gy - px2.w; e[5] = __builtin_amdgcn_exp2f(d * d * NHL2E);
        d = gy - px3.y; e[6] = __builtin_amdgcn_exp2f(d * d * NHL2E);
        d = gy - px3.w; e[7] = __builtin_amdgcn_exp2f(d * d * NHL2E);
        s16x8 v0, v1, v2;
        v0[0]=f2bf(e[0]); v1[0]=f2bf(e[0]*py0.x); v2[0]=f2bf(e[0]*py0.y);
        v0[1]=f2bf(e[1]); v1[1]=f2bf(e[1]*py0.z); v2[1]=f2bf(e[1]*py0.w);
        v0[2]=f2bf(e[2]); v1[2]=f2bf(e[2]*py1.x); v2[2]=f2bf(e[2]*py1.y);
        v0[3]=f2bf(e[3]); v1[3]=f2bf(e[3]*py1.z); v2[3]=f2bf(e[3]*py1.w);
        v0[4]=f2bf(e[4]); v1[4]=f2bf(e[4]*py2.x); v2[4]=f2bf(e[4]*py2.y);
        v0[5]=f2bf(e[5]); v1[5]=f2bf(e[5]*py2.z); v2[5]=f2bf(e[5]*py2.w);
        v0[6]=f2bf(e[6]); v1[6]=f2bf(e[6]*py3.x); v2[6]=f2bf(e[6]*py3.y);
        v0[7]=f2bf(e[7]); v1[7]=f2bf(e[7]*py3.z); v2[7]=f2bf(e[7]*py3.w);
        *(s16x8*)(Bs + (0 * 16 + rn) * LDB + jj) = v0;
        *(s16x8*)(Bs + (1 * 16 + rn) * LDB + jj) = v1;
        *(s16x8*)(Bs + (2 * 16 + rn) * LDB + jj) = v2;
    }
    __syncthreads();

    // --- MFMA phase: wave w takes k-slice [w*128, w*128+128) ----------------
    const int w = tid >> 6, lane = tid & 63;
    const int r = lane & 15, quad = lane >> 4;
    const short* ap = As + r * LDB + w * 128 + quad * 8;
    const short* bp = Bs + r * LDB + w * 128 + quad * 8;

    f32x4 a0 = {0.f, 0.f, 0.f, 0.f}, a1 = a0, a2 = a0;
    #pragma unroll
    for (int kk = 0; kk < 128; kk += 32) {
        s16x8 a  = *(const s16x8*)(ap + kk);
        s16x8 b0 = *(const s16x8*)(bp + kk);
        s16x8 b1 = *(const s16x8*)(bp + 16 * LDB + kk);
        s16x8 b2 = *(const s16x8*)(bp + 32 * LDB + kk);
        a0 = __builtin_amdgcn_mfma_f32_16x16x32_bf16(a, b0, a0, 0, 0, 0);
        a1 = __builtin_amdgcn_mfma_f32_16x16x32_bf16(a, b1, a1, 0, 0, 0);
        a2 = __builtin_amdgcn_mfma_f32_16x16x32_bf16(a, b2, a2, 0, 0, 0);
    }

    // partials [sp][n(384)][m(128)], sp = s*4 + w; acc regs m-consecutive
    // C/D: col(n)=lane&15, row(m)=quad*4+reg  [verified m89/m91]
    float* base = part + (s * 4 + w) * (384 * 128);
    int row = iyt * 16 + r, col = mt * 16 + quad * 4;
    *(f32x4*)(base + (row)       * 128 + col) = a0;
    *(f32x4*)(base + (128 + row) * 128 + col) = a1;
    *(f32x4*)(base + (256 + row) * 128 + col) = a2;
}

// ---- K3: sum 64 splits, divide, store; 256 blocks (all CUs) ----------------
__global__ __launch_bounds__(64) void reduce_kernel(
    const float* __restrict__ part, float* __restrict__ out)
{
    int t = blockIdx.x * 64 + threadIdx.x;    // t = iy*128+ix
    float f0 = 0.f, f1 = 0.f, f2 = 0.f;
    #pragma unroll 8
    for (int s = 0; s < NSPLIT; ++s) {
        const float* p = part + s * (384 * 128);
        f0 += p[t];                 // n = iy        (c=0)
        f1 += p[16384 + t];         // n = 128+iy    (c=1)
        f2 += p[32768 + t];         // n = 256+iy    (c=2)
    }
    float inv = 1.0f / f0;
    out[t]          = f0;           // denom channel: NOT divided
    out[16384 + t]  = f1 * inv;
    out[32768 + t]  = f2 * inv;
}

// ---- Fallback: proven R1 single-kernel (if ws too small) -------------------
#define TS 1024
__global__ __launch_bounds__(256, 4) void convcnp_fallback(
    const float* __restrict__ X, const float* __restrict__ Y, float* __restrict__ out)
{
    __shared__ float4 tile[TS];
    const int tid = threadIdx.x;
    const int gq  = tid >> 4;
    const int sg  = tid & 15;
    const int gi = blockIdx.x * 16 + gq;
    const int ix = gi >> 7, iy = gi & 127;
    const float gx = -2.0f + (float)ix * (4.0f / 127.0f);
    const float gy = -2.0f + (float)iy * (4.0f / 127.0f);
    float s0 = 0.f, s1 = 0.f, s2 = 0.f;
    const float4* X4 = (const float4*)X;
    const float4* Y4 = (const float4*)Y;
    for (int t = 0; t < NPTS / TS; ++t) {
        #pragma unroll
        for (int i = 0; i < TS / 2; i += 256) {
            float4 xa = X4[t * (TS / 2) + i + tid];
            float4 ya = Y4[t * (TS / 2) + i + tid];
            int p = 2 * (i + tid);
            tile[p]     = make_float4(xa.x, xa.y, ya.x, ya.y);
            tile[p + 1] = make_float4(xa.z, xa.w, ya.z, ya.w);
        }
        __syncthreads();
        #pragma unroll 8
        for (int j = 0; j < TS / 16; ++j) {
            float4 p = tile[j * 16 + sg];
            float dx = gx - p.x, dy = gy - p.y;
            float k = __expf(-0.5f * (dx * dx + dy * dy));
            s0 += k; s1 += k * p.z; s2 += k * p.w;
        }
        __syncthreads();
    }
    #pragma unroll
    for (int off = 8; off >= 1; off >>= 1) {
        s0 += __shfl_down(s0, off, 16);
        s1 += __shfl_down(s1, off, 16);
        s2 += __shfl_down(s2, off, 16);
    }
    if (sg == 0) {
        const int o = iy * 128 + ix;
        float inv = 1.0f / s0;
        out[o] = s0; out[GSIZE + o] = s1 * inv; out[2 * GSIZE + o] = s2 * inv;
    }
}

extern "C" void kernel_launch(void* const* d_in, const int* in_sizes, int n_in,
                              void* d_out, int out_size, void* d_ws, size_t ws_size,
                              hipStream_t stream) {
    const float* X = (const float*)d_in[0];
    const float* Y = (const float*)d_in[1];
    float* out = (float*)d_out;
    if (ws_size >= WS_NEEDED) {
        float* part = (float*)d_ws;
        fused_kernel<<<1024, 256, 0, stream>>>(X, Y, part);
        reduce_kernel<<<GSIZE / 64, 64, 0, stream>>>(part, out);
    } else {
        convcnp_fallback<<<GSIZE / 16, 256, 0, stream>>>(X, Y, out);
    }
}

// Round 7
// 66.927 us; speedup vs baseline: 1.2609x; 1.0870x over previous
//
#include <hip/hip_runtime.h>

typedef __attribute__((ext_vector_type(8))) short s16x8;   // 8 bf16 (4 VGPRs)
typedef __attribute__((ext_vector_type(4))) short s16x4;   // 4 bf16 (2 VGPRs)
typedef __attribute__((ext_vector_type(4))) float f32x4;

#define NPTS    8192
#define GSIZE   16384
#define NHL2E   (-0.7213475204444817f)   // -0.5 * log2(e)
#define NSPLIT  32                       // K splits (KCH = 256 each)
#define NBLK    512                      // 4 mt x 4 iyt x 32 s

#define WS_NEEDED ((size_t)NBLK * 3072 * 4)   // 6.3 MB partials

__device__ __forceinline__ short f2bf(float f) {   // RNE float->bf16 bits
    unsigned int u = __builtin_bit_cast(unsigned int, f);
    u += 0x7FFF + ((u >> 16) & 1);
    return (short)(u >> 16);
}

// ---- F: fused gen(A,B in LDS) + MFMA; tile = 32m x 32n x 256k per block ----
// A[m][k] = exp(-.5(xs[mt*32+m]-X[k,0])^2); B_c[n][k] = exp(-.5(ys[iyt*32+n]
// -X[k,1])^2) * {1, Y[k,0], Y[k,1]}.  4 waves = 2x2 quadrants of 16x16.
// Partials: block-contiguous [b][ch(3)][n(32)][m(32)] -> coalesced stores.
__global__ __launch_bounds__(256) void fused32_kernel(
    const float* __restrict__ X, const float* __restrict__ Y,
    float* __restrict__ part)
{
    __shared__ __align__(16) short As[32 * 256];   // 16 KB
    __shared__ __align__(16) short Bs[96 * 256];   // 48 KB  (total 64 KB)

    const int tid = threadIdx.x;
    const int b   = blockIdx.x;            // 512 blocks
    const int s    = b & (NSPLIT - 1);
    const int rest = b >> 5;
    const int mt = rest & 3, iyt = rest >> 2;

    // --- gen: thread = 8 rows x 4 cols (rg = tid>>6, cb = tid&63) -----------
    const int rg = tid >> 6, cb = tid & 63;
    const float4* X4 = (const float4*)X;   // {x0(k), x1(k), x0(k+1), x1(k+1)}
    const float4* Y4 = (const float4*)Y;
    const int base = s * 128 + cb * 2;     // float4 index (k0 = s*256 + cb*4)
    float4 px0 = X4[base], px1 = X4[base + 1];
    float4 py0 = Y4[base], py1 = Y4[base + 1];
    const float xk[4] = {px0.x, px0.z, px1.x, px1.z};   // X[k,0]
    const float yk[4] = {px0.y, px0.w, px1.y, px1.w};   // X[k,1]
    const float w0[4] = {py0.x, py0.z, py1.x, py1.z};   // Y[k,0]
    const float w1[4] = {py0.y, py0.w, py1.y, py1.w};   // Y[k,1]

    #pragma unroll
    for (int rr = 0; rr < 8; ++rr) {
        const int rm = rg * 8 + rr;        // row 0..31
        float gx = -2.0f + (float)(mt * 32 + rm) * (4.0f / 127.0f);
        s16x4 va;
        #pragma unroll
        for (int i = 0; i < 4; ++i) {
            float d = gx - xk[i];
            va[i] = f2bf(__builtin_amdgcn_exp2f(d * d * NHL2E));
        }
        *(s16x4*)(As + rm * 256 + cb * 4) = va;

        float gy = -2.0f + (float)(iyt * 32 + rm) * (4.0f / 127.0f);
        s16x4 v0, v1, v2;
        #pragma unroll
        for (int i = 0; i < 4; ++i) {
            float d = gy - yk[i];
            float e = __builtin_amdgcn_exp2f(d * d * NHL2E);
            v0[i] = f2bf(e); v1[i] = f2bf(e * w0[i]); v2[i] = f2bf(e * w1[i]);
        }
        *(s16x4*)(Bs + (rm)      * 256 + cb * 4) = v0;
        *(s16x4*)(Bs + (32 + rm) * 256 + cb * 4) = v1;
        *(s16x4*)(Bs + (64 + rm) * 256 + cb * 4) = v2;
    }
    __syncthreads();

    // --- MFMA: wave w -> quadrant (wm, wn); full K=256 ----------------------
    const int w = tid >> 6, lane = tid & 63;
    const int wm = w & 1, wn = w >> 1;
    const int r = lane & 15, quad = lane >> 4;
    const short* ap = As + (wm * 16 + r) * 256 + quad * 8;
    const short* bp = Bs + (wn * 16 + r) * 256 + quad * 8;

    f32x4 a0 = {0.f, 0.f, 0.f, 0.f}, a1 = a0, a2 = a0;
    #pragma unroll
    for (int kk = 0; kk < 256; kk += 32) {
        s16x8 a  = *(const s16x8*)(ap + kk);
        s16x8 b0 = *(const s16x8*)(bp + kk);
        s16x8 b1 = *(const s16x8*)(bp + 32 * 256 + kk);
        s16x8 b2 = *(const s16x8*)(bp + 64 * 256 + kk);
        a0 = __builtin_amdgcn_mfma_f32_16x16x32_bf16(a, b0, a0, 0, 0, 0);
        a1 = __builtin_amdgcn_mfma_f32_16x16x32_bf16(a, b1, a1, 0, 0, 0);
        a2 = __builtin_amdgcn_mfma_f32_16x16x32_bf16(a, b2, a2, 0, 0, 0);
    }

    // C/D: col(n)=lane&15, row(m)=quad*4+reg [verified m89/m91]
    float* dst = part + b * 3072;
    const int off = (wn * 16 + r) * 32 + wm * 16 + quad * 4;
    *(f32x4*)(dst + off)        = a0;
    *(f32x4*)(dst + 1024 + off) = a1;
    *(f32x4*)(dst + 2048 + off) = a2;
}

// ---- R: one thread per (iy,ix): sum 32 splits x 3 ch, divide, store --------
__global__ __launch_bounds__(256) void reduce32_kernel(
    const float* __restrict__ part, float* __restrict__ out)
{
    const int t = blockIdx.x * 256 + threadIdx.x;   // 64 blocks, t = iy*128+ix
    const int iy = t >> 7, ix = t & 127;
    const int iyt = iy >> 5, nl = iy & 31, mt = ix >> 5, ml = ix & 31;
    const float* p = part + (size_t)((iyt * 4 + mt) * 32) * 3072 + nl * 32 + ml;
    float f0 = 0.f, f1 = 0.f, f2 = 0.f;
    #pragma unroll 8
    for (int s = 0; s < NSPLIT; ++s) {
        const float* q = p + s * 3072;
        f0 += q[0]; f1 += q[1024]; f2 += q[2048];
    }
    float inv = 1.0f / f0;
    out[t]          = f0;            // denom channel: NOT divided
    out[16384 + t]  = f1 * inv;
    out[32768 + t]  = f2 * inv;
}

// ---- Fallback: proven R1 single-kernel (if ws too small) -------------------
#define TS 1024
__global__ __launch_bounds__(256, 4) void convcnp_fallback(
    const float* __restrict__ X, const float* __restrict__ Y, float* __restrict__ out)
{
    __shared__ float4 tile[TS];
    const int tid = threadIdx.x;
    const int gq  = tid >> 4;
    const int sg  = tid & 15;
    const int gi = blockIdx.x * 16 + gq;
    const int ix = gi >> 7, iy = gi & 127;
    const float gx = -2.0f + (float)ix * (4.0f / 127.0f);
    const float gy = -2.0f + (float)iy * (4.0f / 127.0f);
    float s0 = 0.f, s1 = 0.f, s2 = 0.f;
    const float4* X4 = (const float4*)X;
    const float4* Y4 = (const float4*)Y;
    for (int t = 0; t < NPTS / TS; ++t) {
        #pragma unroll
        for (int i = 0; i < TS / 2; i += 256) {
            float4 xa = X4[t * (TS / 2) + i + tid];
            float4 ya = Y4[t * (TS / 2) + i + tid];
            int p = 2 * (i + tid);
            tile[p]     = make_float4(xa.x, xa.y, ya.x, ya.y);
            tile[p + 1] = make_float4(xa.z, xa.w, ya.z, ya.w);
        }
        __syncthreads();
        #pragma unroll 8
        for (int j = 0; j < TS / 16; ++j) {
            float4 p = tile[j * 16 + sg];
            float dx = gx - p.x, dy = gy - p.y;
            float k = __expf(-0.5f * (dx * dx + dy * dy));
            s0 += k; s1 += k * p.z; s2 += k * p.w;
        }
        __syncthreads();
    }
    #pragma unroll
    for (int off = 8; off >= 1; off >>= 1) {
        s0 += __shfl_down(s0, off, 16);
        s1 += __shfl_down(s1, off, 16);
        s2 += __shfl_down(s2, off, 16);
    }
    if (sg == 0) {
        const int o = iy * 128 + ix;
        float inv = 1.0f / s0;
        out[o] = s0; out[GSIZE + o] = s1 * inv; out[2 * GSIZE + o] = s2 * inv;
    }
}

extern "C" void kernel_launch(void* const* d_in, const int* in_sizes, int n_in,
                              void* d_out, int out_size, void* d_ws, size_t ws_size,
                              hipStream_t stream) {
    const float* X = (const float*)d_in[0];
    const float* Y = (const float*)d_in[1];
    float* out = (float*)d_out;
    if (ws_size >= WS_NEEDED) {
        float* part = (float*)d_ws;
        fused32_kernel<<<NBLK, 256, 0, stream>>>(X, Y, part);
        reduce32_kernel<<<GSIZE / 256, 256, 0, stream>>>(part, out);
    } else {
        convcnp_fallback<<<GSIZE / 16, 256, 0, stream>>>(X, Y, out);
    }
}

// Round 9
// 63.803 us; speedup vs baseline: 1.3226x; 1.0490x over previous
//
#include <hip/hip_runtime.h>
#include <hip/hip_bf16.h>

typedef __attribute__((ext_vector_type(8))) short s16x8;   // 8 bf16 (4 VGPRs)
typedef __attribute__((ext_vector_type(4))) float f32x4;

#define NPTS    8192
#define GSIZE   16384
#define NHL2E   (-0.7213475204444817f)   // -0.5 * log2(e)
#define NSPLIT  32                       // K splits (KCH = 256 each)
#define NBLK    512                      // 4 mt x 4 iyt x 32 s

#define WS_NEEDED ((size_t)NBLK * 3072 * 4)   // 6.3 MB partials

__device__ __forceinline__ unsigned int pk2(float a, float b) {
    // v_cvt_pk_bf16_f32 (RNE) on gfx950: 1 instr for 2 elements
    __hip_bfloat162 h = __float22bfloat162_rn(make_float2(a, b));
    unsigned int u;
    __builtin_memcpy(&u, &h, sizeof(u));   // no-op register alias
    return u;
}

// ---- F: fused gen(A,B in LDS) + MFMA; tile = 32m x 32n x 256k per block ----
// A[m][k] = exp(-.5(xs[mt*32+m]-X[k,0])^2); B_c[n][k] = exp(-.5(ys[iyt*32+n]
// -X[k,1])^2) * {1, Y[k,0], Y[k,1]}.  4 waves = 2x2 quadrants of 16x16.
// Partials: block-contiguous [b][ch(3)][n(32)][m(32)] -> coalesced stores.
__global__ __launch_bounds__(256) void fused32_kernel(
    const float* __restrict__ X, const float* __restrict__ Y,
    float* __restrict__ part)
{
    __shared__ __align__(16) short As[32 * 256];   // 16 KB
    __shared__ __align__(16) short Bs[96 * 256];   // 48 KB  (total 64 KB)

    const int tid = threadIdx.x;
    const int b   = blockIdx.x;            // 512 blocks
    const int s    = b & (NSPLIT - 1);
    const int rest = b >> 5;
    const int mt = rest & 3, iyt = rest >> 2;

    // --- gen: thread = 8 rows x 4 cols (rg = tid>>6, cb = tid&63) -----------
    const int rg = tid >> 6, cb = tid & 63;
    const float4* X4 = (const float4*)X;   // {x0(k), x1(k), x0(k+1), x1(k+1)}
    const float4* Y4 = (const float4*)Y;
    const int base = s * 128 + cb * 2;     // float4 index (k0 = s*256 + cb*4)
    float4 px0 = X4[base], px1 = X4[base + 1];
    float4 py0 = Y4[base], py1 = Y4[base + 1];
    const float xk[4] = {px0.x, px0.z, px1.x, px1.z};   // X[k,0]
    const float yk[4] = {px0.y, px0.w, px1.y, px1.w};   // X[k,1]
    const float w0[4] = {py0.x, py0.z, py1.x, py1.z};   // Y[k,0]
    const float w1[4] = {py0.y, py0.w, py1.y, py1.w};   // Y[k,1]

    #pragma unroll
    for (int rr = 0; rr < 8; ++rr) {
        const int rm = rg * 8 + rr;        // row 0..31
        float gx = -2.0f + (float)(mt * 32 + rm) * (4.0f / 127.0f);
        float a[4];
        #pragma unroll
        for (int i = 0; i < 4; ++i) {
            float d = gx - xk[i];
            a[i] = __builtin_amdgcn_exp2f(d * d * NHL2E);
        }
        uint2 va;
        va.x = pk2(a[0], a[1]); va.y = pk2(a[2], a[3]);
        *(uint2*)(As + rm * 256 + cb * 4) = va;

        float gy = -2.0f + (float)(iyt * 32 + rm) * (4.0f / 127.0f);
        float e[4];
        #pragma unroll
        for (int i = 0; i < 4; ++i) {
            float d = gy - yk[i];
            e[i] = __builtin_amdgcn_exp2f(d * d * NHL2E);
        }
        uint2 v0, v1, v2;
        v0.x = pk2(e[0], e[1]);             v0.y = pk2(e[2], e[3]);
        v1.x = pk2(e[0]*w0[0], e[1]*w0[1]); v1.y = pk2(e[2]*w0[2], e[3]*w0[3]);
        v2.x = pk2(e[0]*w1[0], e[1]*w1[1]); v2.y = pk2(e[2]*w1[2], e[3]*w1[3]);
        *(uint2*)(Bs + (rm)      * 256 + cb * 4) = v0;
        *(uint2*)(Bs + (32 + rm) * 256 + cb * 4) = v1;
        *(uint2*)(Bs + (64 + rm) * 256 + cb * 4) = v2;
    }
    __syncthreads();

    // --- MFMA: wave w -> quadrant (wm, wn); full K=256 ----------------------
    const int w = tid >> 6, lane = tid & 63;
    const int wm = w & 1, wn = w >> 1;
    const int r = lane & 15, quad = lane >> 4;
    const short* ap = As + (wm * 16 + r) * 256 + quad * 8;
    const short* bp = Bs + (wn * 16 + r) * 256 + quad * 8;

    f32x4 a0 = {0.f, 0.f, 0.f, 0.f}, a1 = a0, a2 = a0;
    #pragma unroll
    for (int kk = 0; kk < 256; kk += 32) {
        s16x8 a  = *(const s16x8*)(ap + kk);
        s16x8 b0 = *(const s16x8*)(bp + kk);
        s16x8 b1 = *(const s16x8*)(bp + 32 * 256 + kk);
        s16x8 b2 = *(const s16x8*)(bp + 64 * 256 + kk);
        a0 = __builtin_amdgcn_mfma_f32_16x16x32_bf16(a, b0, a0, 0, 0, 0);
        a1 = __builtin_amdgcn_mfma_f32_16x16x32_bf16(a, b1, a1, 0, 0, 0);
        a2 = __builtin_amdgcn_mfma_f32_16x16x32_bf16(a, b2, a2, 0, 0, 0);
    }

    // C/D: col(n)=lane&15, row(m)=quad*4+reg [verified m89/m91]
    float* dst = part + b * 3072;
    const int off = (wn * 16 + r) * 32 + wm * 16 + quad * 4;
    *(f32x4*)(dst + off)        = a0;
    *(f32x4*)(dst + 1024 + off) = a1;
    *(f32x4*)(dst + 2048 + off) = a2;
}

// ---- R: 256 blocks x 256 thr; thread = (output, split-quarter); LDS combine -
__global__ __launch_bounds__(256) void reduce32_kernel(
    const float* __restrict__ part, float* __restrict__ out)
{
    __shared__ float red[4][3][64];                 // 3 KB
    const int tid = threadIdx.x;
    const int ol = tid & 63, q = tid >> 6;
    const int o = blockIdx.x * 64 + ol;             // o = iy*128 + ix
    const int iy = o >> 7, ix = o & 127;
    const int iyt = iy >> 5, nl = iy & 31, mt = ix >> 5, ml = ix & 31;
    const float* p = part + (size_t)((iyt * 4 + mt) * 32 + q * 8) * 3072
                     + nl * 32 + ml;
    float f0 = 0.f, f1 = 0.f, f2 = 0.f;
    #pragma unroll
    for (int s = 0; s < 8; ++s) {                   // 24 independent loads
        const float* qp = p + s * 3072;
        f0 += qp[0]; f1 += qp[1024]; f2 += qp[2048];
    }
    red[q][0][ol] = f0; red[q][1][ol] = f1; red[q][2][ol] = f2;
    __syncthreads();
    if (tid < 64) {
        float g0 = red[0][0][tid] + red[1][0][tid] + red[2][0][tid] + red[3][0][tid];
        float g1 = red[0][1][tid] + red[1][1][tid] + red[2][1][tid] + red[3][1][tid];
        float g2 = red[0][2][tid] + red[1][2][tid] + red[2][2][tid] + red[3][2][tid];
        float inv = 1.0f / g0;
        int oo = blockIdx.x * 64 + tid;
        out[oo]          = g0;                      // denom: NOT divided
        out[16384 + oo]  = g1 * inv;
        out[32768 + oo]  = g2 * inv;
    }
}

// ---- Fallback: proven R1 single-kernel (if ws too small) -------------------
#define TS 1024
__global__ __launch_bounds__(256, 4) void convcnp_fallback(
    const float* __restrict__ X, const float* __restrict__ Y, float* __restrict__ out)
{
    __shared__ float4 tile[TS];
    const int tid = threadIdx.x;
    const int gq  = tid >> 4;
    const int sg  = tid & 15;
    const int gi = blockIdx.x * 16 + gq;
    const int ix = gi >> 7, iy = gi & 127;
    const float gx = -2.0f + (float)ix * (4.0f / 127.0f);
    const float gy = -2.0f + (float)iy * (4.0f / 127.0f);
    float s0 = 0.f, s1 = 0.f, s2 = 0.f;
    const float4* X4 = (const float4*)X;
    const float4* Y4 = (const float4*)Y;
    for (int t = 0; t < NPTS / TS; ++t) {
        #pragma unroll
        for (int i = 0; i < TS / 2; i += 256) {
            float4 xa = X4[t * (TS / 2) + i + tid];
            float4 ya = Y4[t * (TS / 2) + i + tid];
            int p = 2 * (i + tid);
            tile[p]     = make_float4(xa.x, xa.y, ya.x, ya.y);
            tile[p + 1] = make_float4(xa.z, xa.w, ya.z, ya.w);
        }
        __syncthreads();
        #pragma unroll 8
        for (int j = 0; j < TS / 16; ++j) {
            float4 p = tile[j * 16 + sg];
            float dx = gx - p.x, dy = gy - p.y;
            float k = __expf(-0.5f * (dx * dx + dy * dy));
            s0 += k; s1 += k * p.z; s2 += k * p.w;
        }
        __syncthreads();
    }
    #pragma unroll
    for (int off = 8; off >= 1; off >>= 1) {
        s0 += __shfl_down(s0, off, 16);
        s1 += __shfl_down(s1, off, 16);
        s2 += __shfl_down(s2, off, 16);
    }
    if (sg == 0) {
        const int o = iy * 128 + ix;
        float inv = 1.0f / s0;
        out[o] = s0; out[GSIZE + o] = s1 * inv; out[2 * GSIZE + o] = s2 * inv;
    }
}

extern "C" void kernel_launch(void* const* d_in, const int* in_sizes, int n_in,
                              void* d_out, int out_size, void* d_ws, size_t ws_size,
                              hipStream_t stream) {
    const float* X = (const float*)d_in[0];
    const float* Y = (const float*)d_in[1];
    float* out = (float*)d_out;
    if (ws_size >= WS_NEEDED) {
        float* part = (float*)d_ws;
        fused32_kernel<<<NBLK, 256, 0, stream>>>(X, Y, part);
        reduce32_kernel<<<GSIZE / 64, 256, 0, stream>>>(part, out);
    } else {
        convcnp_fallback<<<GSIZE / 16, 256, 0, stream>>>(X, Y, out);
    }
}